// Round 1
// baseline (146.932 us; speedup 1.0000x reference)
//
#include <hip/hip_runtime.h>

// 21-qubit HEA state-vector simulation, fp32, all real (RY/CNOT are real).
// State lives in d_ws (2^21 floats = 8 MB). Layer-1 (RY product state + CNOT
// chain = Gray map x = y ^ (y>>1)) is computed in closed form inside kernel A.
// Remaining gates are applied as in-register butterflies over bit-groups:
//   A : init + layer2 RY(q0..5)  + chain CNOT(0,1)..(4,5) folded into store perm
//   B1: layer2 RY(q6..10) + CNOT(5,6)..(9,10)   (regs = index bits 14..10)
//   B2: layer2 RY(q11..15)+ CNOT(10,11)..(14,15)(regs = bits 9..5)
//   B3: layer2 RY(q16..20)+ CNOT(15,16)..(19,20)+ layer3 RY(q16..20) (bits 4..0)
//   C : layer3 RY(q0..5)                         (regs = bits 20..15)
//   D1: layer3 RY(q6..10)                        (bits 14..10)
//   D2: layer3 RY(q11..15) + output write        (bits 9..5)
// qubit q <-> index bit (20-q). Norm is preserved by unitarity (skip divide).

#define NQ 21
#define NSTATE (1 << NQ)

__device__ __forceinline__ float2 cs_of(const float* __restrict__ p, int i) {
  float h = 0.5f * p[i];
  return make_float2(cosf(h), sinf(h));
}

template <int BIT, int N>
__device__ __forceinline__ void ry_bf(float (&v)[N], float c, float s) {
#pragma unroll
  for (int m = 0; m < N; ++m) {
    if ((m & (1 << BIT)) == 0) {
      float a = v[m];
      float b = v[m | (1 << BIT)];
      v[m] = c * a - s * b;
      v[m | (1 << BIT)] = s * a + c * b;
    }
  }
}

// CNOT with both control (CBIT) and target (TBIT) inside the register group.
template <int CBIT, int TBIT, int N>
__device__ __forceinline__ void cnot_rr(float (&v)[N]) {
#pragma unroll
  for (int m = 0; m < N; ++m) {
    if ((m & (1 << CBIT)) && !(m & (1 << TBIT))) {
      float t = v[m];
      v[m] = v[m | (1 << TBIT)];
      v[m | (1 << TBIT)] = t;
    }
  }
}

// CNOT whose control bit lives in the thread id: conditional bit-flip of TBIT.
template <int TBIT, int N>
__device__ __forceinline__ void cswap_bf(float (&v)[N], bool cond) {
#pragma unroll
  for (int m = 0; m < N; ++m) {
    if ((m & (1 << TBIT)) == 0) {
      float a = v[m], b = v[m | (1 << TBIT)];
      v[m] = cond ? b : a;
      v[m | (1 << TBIT)] = cond ? a : b;
    }
  }
}

// ---- Kernel A: closed-form layer1+chain1, layer2 RY(q0..5), chain2 C0..C4 ----
__global__ __launch_bounds__(256) void kA(const float* __restrict__ p,
                                          float* __restrict__ st) {
  const int l = blockIdx.x * 256 + threadIdx.x;  // low 15 bits, 0..32767
  const int gl = l ^ (l >> 1);                   // Gray map, low part
  // product over index bits 0..13 (qubit 20-b -> param 20-b)
  float common = 1.0f;
#pragma unroll
  for (int b = 0; b < 14; ++b) {
    float h = 0.5f * p[20 - b];
    float c = cosf(h), s = sinf(h);
    common *= ((gl >> b) & 1) ? s : c;
  }
  // bit14 (qubit 6, param 6): its Gray value flips with h' parity (bit15 of y)
  float h14 = 0.5f * p[6];
  float c14 = cosf(h14), s14 = sinf(h14);
  const int b14 = (gl >> 14) & 1;
  const float plow0 = common * (b14 ? s14 : c14);  // h' even
  const float plow1 = common * (b14 ? c14 : s14);  // h' odd
  // high factors: x bit (15+j) = bit j of (h' ^ (h'>>1)), param index 5-j
  float ch[6], sh[6];
#pragma unroll
  for (int j = 0; j < 6; ++j) {
    float hh = 0.5f * p[5 - j];
    ch[j] = cosf(hh);
    sh[j] = sinf(hh);
  }
  float v[64];
#pragma unroll
  for (int hp = 0; hp < 64; ++hp) {
    const int gh = hp ^ (hp >> 1);
    float prod = (hp & 1) ? plow1 : plow0;
#pragma unroll
    for (int j = 0; j < 6; ++j) prod *= ((gh >> j) & 1) ? sh[j] : ch[j];
    v[hp] = prod;
  }
  // layer-2 RY on qubits 0..5 (q -> h-bit 5-q), params 21+q
  { float2 w = cs_of(p, 21); ry_bf<5>(v, w.x, w.y); }
  { float2 w = cs_of(p, 22); ry_bf<4>(v, w.x, w.y); }
  { float2 w = cs_of(p, 23); ry_bf<3>(v, w.x, w.y); }
  { float2 w = cs_of(p, 24); ry_bf<2>(v, w.x, w.y); }
  { float2 w = cs_of(p, 25); ry_bf<1>(v, w.x, w.y); }
  { float2 w = cs_of(p, 26); ry_bf<0>(v, w.x, w.y); }
  // store with chain CNOT(0,1)..(4,5) folded: h -> prefix-XOR-from-MSB(h)
#pragma unroll
  for (int hh = 0; hh < 64; ++hh) {
    int t = hh ^ (hh >> 1);
    t ^= t >> 2;
    t ^= t >> 4;
    st[(t << 15) | l] = v[hh];
  }
}

// ---- Kernel C: layer3 RY on qubits 0..5 (bits 20..15), params 42..47 ----
__global__ __launch_bounds__(256) void kC(const float* __restrict__ p,
                                          float* __restrict__ st) {
  const int l = blockIdx.x * 256 + threadIdx.x;
  float v[64];
#pragma unroll
  for (int h = 0; h < 64; ++h) v[h] = st[(h << 15) | l];
  { float2 w = cs_of(p, 42); ry_bf<5>(v, w.x, w.y); }
  { float2 w = cs_of(p, 43); ry_bf<4>(v, w.x, w.y); }
  { float2 w = cs_of(p, 44); ry_bf<3>(v, w.x, w.y); }
  { float2 w = cs_of(p, 45); ry_bf<2>(v, w.x, w.y); }
  { float2 w = cs_of(p, 46); ry_bf<1>(v, w.x, w.y); }
  { float2 w = cs_of(p, 47); ry_bf<0>(v, w.x, w.y); }
#pragma unroll
  for (int h = 0; h < 64; ++h) st[(h << 15) | l] = v[h];
}

// ---- kMid: regs = bits 14..10 (qubits 6..10). DO_CNOT adds C5..C9. ----
template <bool DO_CNOT>
__global__ __launch_bounds__(256) void kMid(const float* __restrict__ p,
                                            float* __restrict__ st, int pbase) {
  const int T = blockIdx.x * 256 + threadIdx.x;  // 0..65535
  const int low10 = T & 1023;                    // bits 9..0
  const int high6 = T >> 10;                     // bits 20..15
  const int base = (high6 << 15) | low10;
  float v[32];
#pragma unroll
  for (int r = 0; r < 32; ++r) v[r] = st[base | (r << 10)];
  { float2 w = cs_of(p, pbase + 0); ry_bf<4>(v, w.x, w.y); }  // q6  <-> bit14
  { float2 w = cs_of(p, pbase + 1); ry_bf<3>(v, w.x, w.y); }
  { float2 w = cs_of(p, pbase + 2); ry_bf<2>(v, w.x, w.y); }
  { float2 w = cs_of(p, pbase + 3); ry_bf<1>(v, w.x, w.y); }
  { float2 w = cs_of(p, pbase + 4); ry_bf<0>(v, w.x, w.y); }  // q10 <-> bit10
  if (DO_CNOT) {
    cswap_bf<4>(v, (high6 & 1) != 0);  // CNOT(5,6): control = index bit15
    cnot_rr<4, 3>(v);                  // CNOT(6,7)
    cnot_rr<3, 2>(v);
    cnot_rr<2, 1>(v);
    cnot_rr<1, 0>(v);                  // CNOT(9,10)
  }
#pragma unroll
  for (int r = 0; r < 32; ++r) st[base | (r << 10)] = v[r];
}

// ---- kLow5: regs = bits 9..5 (qubits 11..15). DO_CNOT adds C10..C14.
// outmode: 0 = write st, 1 = real-only out, 2 = interleaved complex out ----
template <bool DO_CNOT>
__global__ __launch_bounds__(256) void kLow5(const float* __restrict__ p,
                                             float* __restrict__ st, int pbase,
                                             float* __restrict__ out,
                                             int outmode) {
  const int T = blockIdx.x * 256 + threadIdx.x;  // 0..65535
  const int low5 = T & 31;                       // bits 4..0
  const int high11 = T >> 5;                     // bits 20..10
  const int base = (high11 << 10) | low5;
  float v[32];
#pragma unroll
  for (int r = 0; r < 32; ++r) v[r] = st[base | (r << 5)];
  { float2 w = cs_of(p, pbase + 0); ry_bf<4>(v, w.x, w.y); }  // q11 <-> bit9
  { float2 w = cs_of(p, pbase + 1); ry_bf<3>(v, w.x, w.y); }
  { float2 w = cs_of(p, pbase + 2); ry_bf<2>(v, w.x, w.y); }
  { float2 w = cs_of(p, pbase + 3); ry_bf<1>(v, w.x, w.y); }
  { float2 w = cs_of(p, pbase + 4); ry_bf<0>(v, w.x, w.y); }  // q15 <-> bit5
  if (DO_CNOT) {
    cswap_bf<4>(v, (high11 & 1) != 0);  // CNOT(10,11): control = index bit10
    cnot_rr<4, 3>(v);                   // CNOT(11,12)
    cnot_rr<3, 2>(v);
    cnot_rr<2, 1>(v);
    cnot_rr<1, 0>(v);                   // CNOT(14,15)
  }
  if (outmode == 0) {
#pragma unroll
    for (int r = 0; r < 32; ++r) st[base | (r << 5)] = v[r];
  } else if (outmode == 1) {
#pragma unroll
    for (int r = 0; r < 32; ++r) out[base | (r << 5)] = v[r];
  } else {
    float2* o2 = (float2*)out;
#pragma unroll
    for (int r = 0; r < 32; ++r)
      o2[base | (r << 5)] = make_float2(v[r], 0.0f);  // state is purely real
  }
}

// ---- kB3: regs = bits 4..0 (qubits 16..20): layer2 RY + C15..C19 + layer3 RY
__global__ __launch_bounds__(256) void kB3(const float* __restrict__ p,
                                           float* __restrict__ st) {
  const int T = blockIdx.x * 256 + threadIdx.x;  // bits 20..5, 0..65535
  float4* g4 = (float4*)(st + (T << 5));
  float v[32];
#pragma unroll
  for (int j = 0; j < 8; ++j) {
    float4 q = g4[j];
    v[4 * j + 0] = q.x;
    v[4 * j + 1] = q.y;
    v[4 * j + 2] = q.z;
    v[4 * j + 3] = q.w;
  }
  { float2 w = cs_of(p, 37); ry_bf<4>(v, w.x, w.y); }  // layer2 q16 <-> bit4
  { float2 w = cs_of(p, 38); ry_bf<3>(v, w.x, w.y); }
  { float2 w = cs_of(p, 39); ry_bf<2>(v, w.x, w.y); }
  { float2 w = cs_of(p, 40); ry_bf<1>(v, w.x, w.y); }
  { float2 w = cs_of(p, 41); ry_bf<0>(v, w.x, w.y); }  // layer2 q20
  cswap_bf<4>(v, (T & 1) != 0);  // CNOT(15,16): control = index bit5
  cnot_rr<4, 3>(v);              // CNOT(16,17)
  cnot_rr<3, 2>(v);
  cnot_rr<2, 1>(v);
  cnot_rr<1, 0>(v);              // CNOT(19,20)
  { float2 w = cs_of(p, 58); ry_bf<4>(v, w.x, w.y); }  // layer3 q16
  { float2 w = cs_of(p, 59); ry_bf<3>(v, w.x, w.y); }
  { float2 w = cs_of(p, 60); ry_bf<2>(v, w.x, w.y); }
  { float2 w = cs_of(p, 61); ry_bf<1>(v, w.x, w.y); }
  { float2 w = cs_of(p, 62); ry_bf<0>(v, w.x, w.y); }  // layer3 q20
#pragma unroll
  for (int j = 0; j < 8; ++j)
    g4[j] = make_float4(v[4 * j + 0], v[4 * j + 1], v[4 * j + 2], v[4 * j + 3]);
}

extern "C" void kernel_launch(void* const* d_in, const int* in_sizes, int n_in,
                              void* d_out, int out_size, void* d_ws,
                              size_t ws_size, hipStream_t stream) {
  const float* p = (const float*)d_in[0];  // 63 fp32 params
  float* out = (float*)d_out;
  float* st = (float*)d_ws;  // 2^21 floats = 8 MB scratch state
  const int outmode = (out_size == 2 * NSTATE) ? 2 : 1;

  kA<<<128, 256, 0, stream>>>(p, st);
  kMid<true><<<256, 256, 0, stream>>>(p, st, 27);           // B1
  kLow5<true><<<256, 256, 0, stream>>>(p, st, 32, st, 0);   // B2
  kB3<<<256, 256, 0, stream>>>(p, st);                      // B3 + layer3 q16..20
  kC<<<128, 256, 0, stream>>>(p, st);                       // layer3 q0..5
  kMid<false><<<256, 256, 0, stream>>>(p, st, 48);          // D1
  kLow5<false><<<256, 256, 0, stream>>>(p, st, 53, out, outmode);  // D2 + out
}

// Round 3
// 93.725 us; speedup vs baseline: 1.5677x; 1.5677x over previous
//
#include <hip/hip_runtime.h>

// 21-qubit HEA, fp32, all-real. 3 kernels; regs hold 32 elems/thread, 5-bit
// gate windows in registers, layout switches via swizzled LDS exchange
// (8192-elem block tile). qubit q <-> index bit (20-q). Params: RY1 q->p[q],
// RY2 q->p[21+q], RY3 q->p[42+q]. Chain C_k = CNOT(q_k,q_{k+1}) in order;
// RY2 q_k before C_{k-1},C_k; RY3 q_k after. Norm==1 by unitarity.
//
// Init (layer1 + chain1) closed form: amp(x) = prod_b f_{20-b}(y_b) with
// y_b = x_b ^ x_{b+1}  (LOCAL Gray decode — the inverse of the chain's
// prefix-XOR-from-MSB map; R2's cascade version was the forward map: bug).

#define NQ 21
#define NSTATE (1 << NQ)
#define SW(t) ((t) + ((t) >> 5))  // LDS anti-conflict: +1 word per 32 words

__device__ __forceinline__ float sel(const float* cs, const float* sn, int i,
                                     int bit) {
  return bit ? sn[i] : cs[i];
}

template <int BIT, int N>
__device__ __forceinline__ void ry_bf(float (&v)[N], float c, float s) {
#pragma unroll
  for (int m = 0; m < N; ++m)
    if ((m & (1 << BIT)) == 0) {
      float a = v[m], b = v[m | (1 << BIT)];
      v[m] = c * a - s * b;
      v[m | (1 << BIT)] = s * a + c * b;
    }
}

template <int CBIT, int TBIT, int N>
__device__ __forceinline__ void cnot_rr(float (&v)[N]) {
#pragma unroll
  for (int m = 0; m < N; ++m)
    if ((m & (1 << CBIT)) && !(m & (1 << TBIT))) {
      float t = v[m];
      v[m] = v[m | (1 << TBIT)];
      v[m | (1 << TBIT)] = t;
    }
}

// ============ K1: init + RY2 q14..20 | RY2 q0..4,C0..3,RY3 q0..3 |
//                  RY2 q5, C4, RY3 q4.  Block owns x14..x7 = bid. ============
__global__ __launch_bounds__(256) void k1(const float* __restrict__ p,
                                          float* __restrict__ st) {
  __shared__ float cs[63], sn[63];
  __shared__ float ex[8448];
  const int tid = threadIdx.x;
  if (tid < 63) {
    float h = 0.5f * p[tid];
    cs[tid] = cosf(h);
    sn[tid] = sinf(h);
  }
  __syncthreads();
  const int bid = blockIdx.x;  // bit i = x_{7+i}

  // Layout A: thr[7:2]=x20..15 (tid bit 2+j = x_{15+j}), thr[1:0]=x1,x0;
  //           regs: r bit j = x_{2+j} (x6..x2).
  const int hi6 = tid >> 2;
  const int x1 = (tid >> 1) & 1, x0 = tid & 1;

  // Thread-fixed init factors (y_b = x_b ^ x_{b+1}):
  const int gh = hi6 ^ (hi6 >> 1);  // y_{15+j} = gh_j, param p[5-j]
  const int gm = bid ^ (bid >> 1);  // y_{7+i} = gm_i (i<7), param p[13-i]
  float Pre = sel(cs, sn, 6, ((bid >> 7) ^ hi6) & 1);  // y_14, p[6]
#pragma unroll
  for (int j = 0; j < 6; ++j) Pre *= sel(cs, sn, 5 - j, (gh >> j) & 1);
#pragma unroll
  for (int i = 0; i < 7; ++i) Pre *= sel(cs, sn, 13 - i, (gm >> i) & 1);

  // H-table over (x1,x0), parameterized by a = x2 (= r&1):
  //   base = f_19(x1^a) * f_20(x0^x1)   [y_1 = x1^x2, y_0 = x0^x1]
  //   then RY2 q19 (p[40]) on x1, RY2 q20 (p[41]) on x0.
  float HH[2];
#pragma unroll
  for (int a = 0; a < 2; ++a) {
    float Hm[2][2];
#pragma unroll
    for (int X1 = 0; X1 < 2; ++X1)
#pragma unroll
      for (int X0 = 0; X0 < 2; ++X0)
        Hm[X1][X0] = sel(cs, sn, 19, X1 ^ a) * sel(cs, sn, 20, X0 ^ X1);
    {
      const float c = cs[40], s = sn[40];  // RY2 q19 on x1
#pragma unroll
      for (int X0 = 0; X0 < 2; ++X0) {
        float a0 = Hm[0][X0], a1 = Hm[1][X0];
        Hm[0][X0] = c * a0 - s * a1;
        Hm[1][X0] = s * a0 + c * a1;
      }
    }
    {
      const float c = cs[41], s = sn[41];  // RY2 q20 on x0
#pragma unroll
      for (int X1 = 0; X1 < 2; ++X1) {
        float a0 = Hm[X1][0], a1 = Hm[X1][1];
        Hm[X1][0] = c * a0 - s * a1;
        Hm[X1][1] = s * a0 + c * a1;
      }
    }
    HH[a] = Hm[x1][x0];
  }

  float v[32];
#pragma unroll
  for (int r = 0; r < 32; ++r) {
    const int gr = r ^ (r >> 1);  // y_{2+j} = gr_j (j<4), y_6 = r_4 ^ bid_0
    float prod = Pre * HH[r & 1];
    prod *= sel(cs, sn, 18, gr & 1);
    prod *= sel(cs, sn, 17, (gr >> 1) & 1);
    prod *= sel(cs, sn, 16, (gr >> 2) & 1);
    prod *= sel(cs, sn, 15, (gr >> 3) & 1);
    prod *= sel(cs, sn, 14, ((gr >> 4) ^ bid) & 1);
    v[r] = prod;
  }
  // RY2 q14..q18 on reg bits 4..0 (params 35..39)
  ry_bf<4>(v, cs[35], sn[35]);
  ry_bf<3>(v, cs[36], sn[36]);
  ry_bf<2>(v, cs[37], sn[37]);
  ry_bf<1>(v, cs[38], sn[38]);
  ry_bf<0>(v, cs[39], sn[39]);

  // Exchange A -> B. Canonical tile t[12:7]=x20..15, t[6:0]=x6..0.
#pragma unroll
  for (int r = 0; r < 32; ++r)
    ex[SW((hi6 << 7) | (r << 2) | (tid & 3))] = v[r];
  __syncthreads();
  // Layout B: regs bit j = x_{16+j}; thr bit7=x15, bits6..0=x6..0
#pragma unroll
  for (int r = 0; r < 32; ++r) v[r] = ex[SW((r << 8) | tid)];
  __syncthreads();

  // RY2 q0..q4 (21..25 -> reg bits 4..0), C0..C3, RY3 q0..q3 (42..45)
  ry_bf<4>(v, cs[21], sn[21]);
  ry_bf<3>(v, cs[22], sn[22]);
  ry_bf<2>(v, cs[23], sn[23]);
  ry_bf<1>(v, cs[24], sn[24]);
  ry_bf<0>(v, cs[25], sn[25]);
  cnot_rr<4, 3>(v);
  cnot_rr<3, 2>(v);
  cnot_rr<2, 1>(v);
  cnot_rr<1, 0>(v);
  ry_bf<4>(v, cs[42], sn[42]);
  ry_bf<3>(v, cs[43], sn[43]);
  ry_bf<2>(v, cs[44], sn[44]);
  ry_bf<1>(v, cs[45], sn[45]);

  // Exchange B -> C
#pragma unroll
  for (int r = 0; r < 32; ++r) ex[SW((r << 8) | tid)] = v[r];
  __syncthreads();
  // Layout C: regs bit j = x_{15+j}; thr bit7=x20, bits6..0=x6..0
#pragma unroll
  for (int r = 0; r < 32; ++r)
    v[r] = ex[SW(((tid >> 7) << 12) | (r << 7) | (tid & 127))];

  // RY2 q5 (p26 -> reg bit0), C4 (ctrl x16=bit1, tgt x15=bit0), RY3 q4 (p46)
  ry_bf<0>(v, cs[26], sn[26]);
  cnot_rr<1, 0>(v);
  ry_bf<1>(v, cs[46], sn[46]);

  // Store: x = x20(tid7)|x19..15(r)|x14..7(bid)|x6..0(tid&127). Coalesced.
#pragma unroll
  for (int r = 0; r < 32; ++r)
    st[((tid >> 7) << 20) | (r << 15) | (bid << 7) | (tid & 127)] = v[r];
}

// ============ K2: RY2 q6..9,C5..8,RY3 q5..8 | RY2 q10..13,C9..12,RY3 q9..12.
//                  Block owns x20..16, x6..4. ============
__global__ __launch_bounds__(256) void k2(const float* __restrict__ p,
                                          float* __restrict__ st) {
  __shared__ float cs[63], sn[63];
  __shared__ float ex[8448];
  const int tid = threadIdx.x;
  if (tid < 63) {
    float h = 0.5f * p[tid];
    cs[tid] = cosf(h);
    sn[tid] = sinf(h);
  }
  __syncthreads();
  const int bid = blockIdx.x;
  const int xhi = (bid >> 3) << 16;  // x20..16
  const int xmid = (bid & 7) << 4;   // x6..4

  // Layout A: regs bit j = x_{11+j}; thr[7:4]=x10..7, thr[3:0]=x3..0
  float v[32];
#pragma unroll
  for (int r = 0; r < 32; ++r)
    v[r] = st[xhi | (r << 11) | ((tid >> 4) << 7) | xmid | (tid & 15)];

  // RY2 q6..q9 (27..30 -> reg bits 3..0), C5..C8, RY3 q5..q8 (47..50)
  ry_bf<3>(v, cs[27], sn[27]);
  ry_bf<2>(v, cs[28], sn[28]);
  ry_bf<1>(v, cs[29], sn[29]);
  ry_bf<0>(v, cs[30], sn[30]);
  cnot_rr<4, 3>(v);
  cnot_rr<3, 2>(v);
  cnot_rr<2, 1>(v);
  cnot_rr<1, 0>(v);
  ry_bf<4>(v, cs[47], sn[47]);
  ry_bf<3>(v, cs[48], sn[48]);
  ry_bf<2>(v, cs[49], sn[49]);
  ry_bf<1>(v, cs[50], sn[50]);

  // Exchange. Tile t[12:4]=x15..7, t[3:0]=x3..0.
#pragma unroll
  for (int r = 0; r < 32; ++r) ex[SW((r << 8) | tid)] = v[r];
  __syncthreads();
  // Layout B: regs bit j = x_{7+j}; thr[7:4]=x15..12
#pragma unroll
  for (int r = 0; r < 32; ++r)
    v[r] = ex[SW(((tid >> 4) << 9) | (r << 4) | (tid & 15))];

  // RY2 q10..q13 (31..34 -> reg bits 3..0), C9..C12, RY3 q9..q12 (51..54)
  ry_bf<3>(v, cs[31], sn[31]);
  ry_bf<2>(v, cs[32], sn[32]);
  ry_bf<1>(v, cs[33], sn[33]);
  ry_bf<0>(v, cs[34], sn[34]);
  cnot_rr<4, 3>(v);
  cnot_rr<3, 2>(v);
  cnot_rr<2, 1>(v);
  cnot_rr<1, 0>(v);
  ry_bf<4>(v, cs[51], sn[51]);
  ry_bf<3>(v, cs[52], sn[52]);
  ry_bf<2>(v, cs[53], sn[53]);
  ry_bf<1>(v, cs[54], sn[54]);

#pragma unroll
  for (int r = 0; r < 32; ++r)
    st[xhi | ((tid >> 4) << 12) | (r << 7) | xmid | (tid & 15)] = v[r];
}

// ============ K3: C13..16,RY3 q13..16 | C17..19,RY3 q17..20 + output.
//                  Block owns x20..13. ============
__global__ __launch_bounds__(256) void k3(const float* __restrict__ p,
                                          float* __restrict__ st,
                                          float* __restrict__ out, int outmode) {
  __shared__ float cs[63], sn[63];
  __shared__ float ex[8448];
  const int tid = threadIdx.x;
  if (tid < 63) {
    float h = 0.5f * p[tid];
    cs[tid] = cosf(h);
    sn[tid] = sinf(h);
  }
  __syncthreads();
  const int xb = blockIdx.x << 13;  // x20..13

  // Layout A: regs bit j = x_{3+j}; thr[7:3]=x12..8, thr[2:0]=x2..0
  float v[32];
#pragma unroll
  for (int r = 0; r < 32; ++r)
    v[r] = st[xb | ((tid >> 3) << 8) | (r << 3) | (tid & 7)];

  // C13..C16 (q13=bit4..q17=bit0), RY3 q13..q16 (55..58 -> bits 4..1)
  cnot_rr<4, 3>(v);
  cnot_rr<3, 2>(v);
  cnot_rr<2, 1>(v);
  cnot_rr<1, 0>(v);
  ry_bf<4>(v, cs[55], sn[55]);
  ry_bf<3>(v, cs[56], sn[56]);
  ry_bf<2>(v, cs[57], sn[57]);
  ry_bf<1>(v, cs[58], sn[58]);

  // Exchange. Tile t = x12..0.
#pragma unroll
  for (int r = 0; r < 32; ++r)
    ex[SW(((tid >> 3) << 8) | (r << 3) | (tid & 7))] = v[r];
  __syncthreads();
  // Layout B: regs bit j = x_j; thr = x12..5
#pragma unroll
  for (int r = 0; r < 32; ++r) v[r] = ex[SW((tid << 5) | r)];

  // C17..C19 (q17=bit3..q20=bit0), RY3 q17..q20 (59..62 -> bits 3..0)
  cnot_rr<3, 2>(v);
  cnot_rr<2, 1>(v);
  cnot_rr<1, 0>(v);
  ry_bf<3>(v, cs[59], sn[59]);
  ry_bf<2>(v, cs[60], sn[60]);
  ry_bf<1>(v, cs[61], sn[61]);
  ry_bf<0>(v, cs[62], sn[62]);

  // Output: thread owns 32 consecutive elements at base.
  const int base = xb | (tid << 5);
  if (outmode == 2) {
    float4* o4 = (float4*)out;  // interleaved complex: (re,0) pairs
#pragma unroll
    for (int i = 0; i < 16; ++i)
      o4[(base >> 1) + i] = make_float4(v[2 * i], 0.0f, v[2 * i + 1], 0.0f);
  } else {
    float4* o4 = (float4*)(out + base);
#pragma unroll
    for (int j = 0; j < 8; ++j)
      o4[j] = make_float4(v[4 * j], v[4 * j + 1], v[4 * j + 2], v[4 * j + 3]);
  }
}

extern "C" void kernel_launch(void* const* d_in, const int* in_sizes, int n_in,
                              void* d_out, int out_size, void* d_ws,
                              size_t ws_size, hipStream_t stream) {
  const float* p = (const float*)d_in[0];  // 63 fp32 params
  float* out = (float*)d_out;
  float* st = (float*)d_ws;  // 2^21 floats = 8 MB scratch
  const int outmode = (out_size == 2 * NSTATE) ? 2 : 1;

  k1<<<256, 256, 0, stream>>>(p, st);
  k2<<<256, 256, 0, stream>>>(p, st);
  k3<<<256, 256, 0, stream>>>(p, st, out, outmode);
}